// Round 2
// 420.398 us; speedup vs baseline: 8.4366x; 8.4366x over previous
//
#include <hip/hip_runtime.h>

// Photonic layer: U = product of 2016 MZI 2x2 rotations (Reck mesh), then
// out = x @ U.T (complex), then tiny first-order Kerr phase rotation.
//
// R9 = R8 resubmit + hardening. R8's bench died at the container level
// (no verifier output), so no counter evidence against the design exists.
// Change vs R8: U is staged through the harness-provided d_ws workspace
// (kernel argument) instead of a __device__ global symbol, removing the
// only nonstandard construct as a crash candidate. __device__ g_U remains
// only as a fallback when ws_size < 32 KB.
//
// Design (from R7 rocprof diagnosis: 7.22 GB HBM vs 268 MB ideal, VALUBusy
// 4.3%, VGPR_Count 64 => private arrays in scratch; WRITE_SIZE 5x ideal):
//  (1) U built ONCE by a 1-block/64-thread kernel (__launch_bounds__(64,1)
//      -> 512-VGPR budget keeps the 128-float column state in registers).
//  (2) Apply kernel: 64 complex accumulators in VGPRs (static indices only),
//      x streamed 8 floats at a time (16 live regs, no big private array),
//      U broadcast from LDS via wave-uniform ds_read_b128 (conflict-free).
//  (3) Outputs written as 16+16 contiguous float4 bursts -> full 64B lines.
// Output layout logic (planar re|im vs re-only, selected by out_size) is
// carried over verbatim from the harness-verified R7 kernel.

#define PSIZE 64
#define N_PHASES 2016
#define NLAYER 63            // layers i=1..63
#define LOSS_AMP 0.99426007f
#define NL_COEFF 2.6e-17f
#define U_BYTES (2 * PSIZE * PSIZE * sizeof(float))  // 32 KB

// Fallback U storage if no workspace is provided.
__device__ __align__(16) float g_U_fallback[2 * PSIZE * PSIZE];

__global__ __launch_bounds__(64, 1) void build_kernel(
    const float* __restrict__ phases,
    float* __restrict__ Uout) {          // null -> use g_U_fallback
  __shared__ float2 wsm[NLAYER * NLAYER];  // 31.75 KB of per-slot weights
  const int tid = threadIdx.x;             // 64 threads, one U-column each
  float* Udst = (Uout != nullptr) ? Uout : g_U_fallback;

  // Phase 1: per-slot (L*cos, L*sin) weights (padded 63x63 grid).
  for (int idx = tid; idx < NLAYER * NLAYER; idx += 64) {
    const int li = idx / NLAYER;       // layer 0..62 (mesh layer i = li+1)
    const int m = idx - li * NLAYER;   // slot 0..62
    float2 w;
    if (m <= li) {
      const int p = (li * (li + 1)) / 2 + m;
      const float th = phases[p];
      w = make_float2(LOSS_AMP * cosf(th), LOSS_AMP * sinf(th));
    } else {
      w = make_float2(1.0f, 0.0f);
    }
    wsm[idx] = w;
  }
  __syncthreads();

  // Phase 2: thread tid evolves column tid of U through the MZI chain.
  float ure[PSIZE], uim[PSIZE];
#pragma unroll
  for (int r = 0; r < PSIZE; ++r) {
    ure[r] = (r == tid) ? 1.0f : 0.0f;
    uim[r] = 0.0f;
  }
  for (int li = 0; li < NLAYER; ++li) {
    const float2* w = &wsm[li * NLAYER];
#pragma unroll
    for (int m = 0; m < NLAYER; ++m) {
      if (m <= li) {                   // skip identity pads (uniform branch)
        const float2 ww = w[m];        // wave-uniform LDS broadcast
        const float are = ure[m], aim = uim[m];
        const float bre = ure[m + 1], bim = uim[m + 1];
        // new_a = L*(c*a + i*s*b); new_b = L*(i*s*a + c*b)  (L pre-folded)
        ure[m]     = fmaf(ww.x, are, -ww.y * bim);
        uim[m]     = fmaf(ww.x, aim,  ww.y * bre);
        ure[m + 1] = fmaf(ww.x, bre, -ww.y * aim);
        uim[m + 1] = fmaf(ww.x, bim,  ww.y * are);
      }
    }
  }

  // Write out: float2[r*64 + tid] = U[r][tid]; consecutive lanes coalesce.
#pragma unroll
  for (int r = 0; r < PSIZE; ++r) {
    ((float2*)Udst)[r * PSIZE + tid] = make_float2(ure[r], uim[r]);
  }
}

__global__ __launch_bounds__(256, 2) void apply_kernel(
    const float* __restrict__ Usrc,   // null -> use g_U_fallback
    const float* __restrict__ xr,
    const float* __restrict__ xi,
    float* __restrict__ out_re,
    float* __restrict__ out_im,       // null -> real-part-only output
    int nrows) {
  // U staged once per block; all later reads are wave-uniform broadcasts.
  __shared__ __align__(16) float sU[2 * PSIZE * PSIZE];  // 32 KB
  {
    const float4* g4 = (const float4*)((Usrc != nullptr) ? Usrc : g_U_fallback);
    float4* s4 = (float4*)sU;
    for (int i = threadIdx.x; i < (2 * PSIZE * PSIZE) / 4; i += 256)
      s4[i] = g4[i];
  }
  __syncthreads();

  const int row = blockIdx.x * 256 + threadIdx.x;
  if (row >= nrows) return;  // no barriers after this point

  // row*PSIZE*4 bytes is a multiple of 256 -> float4-aligned.
  const float4* xr4 = (const float4*)(xr + (size_t)row * PSIZE);
  const float4* xi4 = (const float4*)(xi + (size_t)row * PSIZE);

  float aR[PSIZE], aI[PSIZE];  // 128 VGPRs of accumulators, static idx only
#pragma unroll
  for (int j = 0; j < PSIZE; ++j) { aR[j] = 0.0f; aI[j] = 0.0f; }

  const float4* su4 = (const float4*)sU;  // float4 [j*32 + k/2]

#pragma unroll 1
  for (int kc = 0; kc < 8; ++kc) {        // 8 k-values per chunk
    const float4 a0 = xr4[2 * kc];        // x re: k = 8kc .. 8kc+3
    const float4 a1 = xr4[2 * kc + 1];    //       k = 8kc+4 .. 8kc+7
    const float4 b0 = xi4[2 * kc];        // x im
    const float4 b1 = xi4[2 * kc + 1];
    const float4* up = su4 + kc * 4;
#pragma unroll
    for (int j = 0; j < PSIZE; ++j) {
      const float4 u0 = up[j * 32 + 0];   // (Ur,Ui)[j][8kc], [8kc+1]
      const float4 u1 = up[j * 32 + 1];
      const float4 u2 = up[j * 32 + 2];
      const float4 u3 = up[j * 32 + 3];
      float r = aR[j], m = aI[j];
      r = fmaf(a0.x, u0.x, r); r = fmaf(-b0.x, u0.y, r);
      m = fmaf(a0.x, u0.y, m); m = fmaf( b0.x, u0.x, m);
      r = fmaf(a0.y, u0.z, r); r = fmaf(-b0.y, u0.w, r);
      m = fmaf(a0.y, u0.w, m); m = fmaf( b0.y, u0.z, m);
      r = fmaf(a0.z, u1.x, r); r = fmaf(-b0.z, u1.y, r);
      m = fmaf(a0.z, u1.y, m); m = fmaf( b0.z, u1.x, m);
      r = fmaf(a0.w, u1.z, r); r = fmaf(-b0.w, u1.w, r);
      m = fmaf(a0.w, u1.w, m); m = fmaf( b0.w, u1.z, m);
      r = fmaf(a1.x, u2.x, r); r = fmaf(-b1.x, u2.y, r);
      m = fmaf(a1.x, u2.y, m); m = fmaf( b1.x, u2.x, m);
      r = fmaf(a1.y, u2.z, r); r = fmaf(-b1.y, u2.w, r);
      m = fmaf(a1.y, u2.w, m); m = fmaf( b1.y, u2.z, m);
      r = fmaf(a1.z, u3.x, r); r = fmaf(-b1.z, u3.y, r);
      m = fmaf(a1.z, u3.y, m); m = fmaf( b1.z, u3.x, m);
      r = fmaf(a1.w, u3.z, r); r = fmaf(-b1.w, u3.w, r);
      m = fmaf(a1.w, u3.w, m); m = fmaf( b1.w, u3.z, m);
      aR[j] = r; aI[j] = m;
    }
  }

  // Epilogue: Kerr first-order rotation + contiguous float4 burst stores.
  float* orp = out_re + (size_t)row * PSIZE;
  float* oip = (out_im != nullptr) ? (out_im + (size_t)row * PSIZE) : nullptr;
#pragma unroll
  for (int jq = 0; jq < 16; ++jq) {
    const int j = 4 * jq;
    float4 vr, vi;
    {
      const float p = NL_COEFF * fmaf(aR[j], aR[j], aI[j] * aI[j]);
      vr.x = fmaf(-aI[j], p, aR[j]); vi.x = fmaf(aR[j], p, aI[j]);
    }
    {
      const float p = NL_COEFF * fmaf(aR[j+1], aR[j+1], aI[j+1] * aI[j+1]);
      vr.y = fmaf(-aI[j+1], p, aR[j+1]); vi.y = fmaf(aR[j+1], p, aI[j+1]);
    }
    {
      const float p = NL_COEFF * fmaf(aR[j+2], aR[j+2], aI[j+2] * aI[j+2]);
      vr.z = fmaf(-aI[j+2], p, aR[j+2]); vi.z = fmaf(aR[j+2], p, aI[j+2]);
    }
    {
      const float p = NL_COEFF * fmaf(aR[j+3], aR[j+3], aI[j+3] * aI[j+3]);
      vr.w = fmaf(-aI[j+3], p, aR[j+3]); vi.w = fmaf(aR[j+3], p, aI[j+3]);
    }
    ((float4*)orp)[jq] = vr;
    if (oip != nullptr) ((float4*)oip)[jq] = vi;
  }
}

extern "C" void kernel_launch(void* const* d_in, const int* in_sizes, int n_in,
                              void* d_out, int out_size, void* d_ws, size_t ws_size,
                              hipStream_t stream) {
  // Identify inputs by size, not position: phases has exactly 2016 elements.
  int pidx = -1;
  for (int i = 0; i < n_in; ++i) {
    if (in_sizes[i] == N_PHASES) { pidx = i; break; }
  }
  if (pidx < 0) pidx = 2;  // fall back to dict order
  int xa = -1, xb = -1;
  for (int i = 0; i < n_in; ++i) {
    if (i == pidx) continue;
    if (xa < 0) xa = i;
    else if (xb < 0) xb = i;
  }
  if (xa < 0 || xb < 0) return;

  const float* phases = (const float*)d_in[pidx];
  const float* x_real = (const float*)d_in[xa];
  const float* x_imag = (const float*)d_in[xb];

  long b_in = (long)in_sizes[xa] / PSIZE;
  if ((long)in_sizes[xb] / PSIZE < b_in) b_in = (long)in_sizes[xb] / PSIZE;

  float* out = (float*)d_out;
  float* out_re = out;
  float* out_im = nullptr;
  long nrows;

  if ((long)out_size >= 2 * b_in * PSIZE) {
    // PLANAR: [all re (B*64) | all im (B*64)]; im block at out_size/2.
    const long half = (long)out_size / 2;
    out_im = out + half;
    long cap = half / PSIZE;               // rows each block can hold
    nrows = (b_in < cap) ? b_in : cap;
  } else {
    // Real-part-only buffer.
    long cap = (long)out_size / PSIZE;
    nrows = (b_in < cap) ? b_in : cap;
  }
  if (nrows <= 0) return;

  // U buffer: prefer harness workspace; fall back to the device global.
  float* Ubuf = nullptr;
  if (d_ws != nullptr && ws_size >= U_BYTES) Ubuf = (float*)d_ws;

  build_kernel<<<1, 64, 0, stream>>>(phases, Ubuf);

  const int nblocks = (int)((nrows + 255) / 256);
  apply_kernel<<<nblocks, 256, 0, stream>>>(Ubuf, x_real, x_imag,
                                            out_re, out_im, (int)nrows);
}

// Round 3
// 276.367 us; speedup vs baseline: 12.8334x; 1.5212x over previous
//
#include <hip/hip_runtime.h>

// Photonic layer: U = product of 2016 MZI 2x2 rotations (Reck mesh), then
// out = x @ U.T (complex), then tiny first-order Kerr phase rotation.
//
// R10. R9 counters: total 420us = apply 204us (VALU GEMV, VALUBusy 51%,
// LDS pipe co-saturated) + build ~215us (single-wave, per-slot ds_read
// latency chain ~256 cyc/slot). Changes:
//  (1) build: per-layer weights batched into 32 ds_read_b128 -> registers
//      (independent loads, staggered waits) instead of per-slot ds_read.
//      Also emits U as bf16 hi/lo split B-matrices (XOR-swizzled 16B slots)
//      for the MFMA apply path, alongside the f32 U for the tail/fallback.
//  (2) apply: MFMA GEMM (16x16x32 bf16, guide-verified C/D layout).
//      out_re = xr*Ur - xi*Ui, out_im = xr*Ui + xi*Ur, each real product
//      via 3-term bf16 split (hh + hl + lh; lo*lo ~2^-16 dropped).
//      -> compute ~12us on matrix pipe; kernel becomes HBM-bound (~40us floor).
//  (3) R9's VALU apply kept verbatim as tail/fallback kernel.
// absmax is pinned at 2^-6 (bf16-quantized reference); bf16x3 split adds
// ~1e-4 abs error -- negligible vs that floor.

#define PSIZE 64
#define N_PHASES 2016
#define NLAYER 63
#define LOSS_AMP 0.99426007f
#define NL_COEFF 2.6e-17f

#define UF32_BYTES (2 * PSIZE * PSIZE * 4)    // 32 KB f32 complex U
#define WSPLIT_BYTES (4 * PSIZE * PSIZE * 2)  // 32 KB: Urh,Url,Uih,Uil bf16
#define WS_NEED (UF32_BYTES + WSPLIT_BYTES)

typedef __attribute__((ext_vector_type(8))) short sh8;    // 8 bf16 (4 VGPR)
typedef __attribute__((ext_vector_type(4))) float f32x4;  // MFMA C/D

__device__ __align__(16) float g_U_fallback[2 * PSIZE * PSIZE];

__device__ inline unsigned short f32_to_bf16_rn(float f) {
  unsigned int u = __float_as_uint(f);
  u += 0x7fffu + ((u >> 16) & 1u);   // round to nearest even
  return (unsigned short)(u >> 16);
}
__device__ inline float bf16_to_f32(unsigned short h) {
  return __uint_as_float(((unsigned int)h) << 16);
}

// ---------------------------------------------------------------------------
// build: 1 block x 256 threads. Phase 1 (all): weights -> LDS (4 waves).
// Phase 2 (wave 0): thread t evolves column t of U; per-layer weights are
// batch-loaded into 32 float4 registers (independent b128 reads).
// ---------------------------------------------------------------------------
__global__ __launch_bounds__(256, 1) void build_kernel(
    const float* __restrict__ phases,
    float* __restrict__ Uf32,            // null -> g_U_fallback
    unsigned short* __restrict__ Wout) { // null -> skip split output
  __shared__ __align__(16) float2 wsm[NLAYER * 64];  // stride padded to 64
  const int tid = threadIdx.x;

  for (int idx = tid; idx < NLAYER * 64; idx += 256) {
    const int li = idx >> 6;          // layer 0..62 (mesh layer i = li+1)
    const int m = idx & 63;           // slot 0..63 (63 = pad)
    float2 w = make_float2(1.0f, 0.0f);
    if (m <= li && m < NLAYER) {
      const int p = (li * (li + 1)) / 2 + m;
      const float th = phases[p];
      w = make_float2(LOSS_AMP * cosf(th), LOSS_AMP * sinf(th));
    }
    wsm[idx] = w;
  }
  __syncthreads();
  if (tid >= 64) return;

  float ure[PSIZE], uim[PSIZE];
#pragma unroll
  for (int r = 0; r < PSIZE; ++r) {
    ure[r] = (r == tid) ? 1.0f : 0.0f;
    uim[r] = 0.0f;
  }

  for (int li = 0; li < NLAYER; ++li) {
    // Batched layer-weight load: 32 independent ds_read_b128.
    const float4* wrow = (const float4*)&wsm[li * 64];
    float4 wb[32];
#pragma unroll
    for (int q = 0; q < 32; ++q) wb[q] = wrow[q];
#pragma unroll
    for (int m = 0; m < NLAYER; ++m) {
      if (m <= li) {                  // wave-uniform guard
        const float wc = (m & 1) ? wb[m >> 1].z : wb[m >> 1].x;
        const float ws = (m & 1) ? wb[m >> 1].w : wb[m >> 1].y;
        const float are = ure[m], aim = uim[m];
        const float bre = ure[m + 1], bim = uim[m + 1];
        ure[m]     = fmaf(wc, are, -ws * bim);
        uim[m]     = fmaf(wc, aim,  ws * bre);
        ure[m + 1] = fmaf(wc, bre, -ws * aim);
        uim[m + 1] = fmaf(wc, bim,  ws * are);
      }
    }
  }

  // f32 U for tail/fallback: float2[r*64 + c] = U[r][c].
  float* Udst = (Uf32 != nullptr) ? Uf32 : g_U_fallback;
#pragma unroll
  for (int r = 0; r < PSIZE; ++r)
    ((float2*)Udst)[r * PSIZE + tid] = make_float2(ure[r], uim[r]);

  // bf16 split B-matrices: W[mat][n][k] = {Urh,Url,Uih,Uil}[n][k], k = tid.
  // 16B k-slots XOR-swizzled by (n&7) so fragment ds_read_b128 is ~2-way.
  if (Wout != nullptr) {
    const int slot = tid >> 3, kin = tid & 7;
#pragma unroll
    for (int n = 0; n < PSIZE; ++n) {
      const int base = n * 64 + ((slot ^ (n & 7)) << 3) + kin;
      const unsigned short rh = f32_to_bf16_rn(ure[n]);
      const unsigned short rl = f32_to_bf16_rn(ure[n] - bf16_to_f32(rh));
      const unsigned short ih = f32_to_bf16_rn(uim[n]);
      const unsigned short il = f32_to_bf16_rn(uim[n] - bf16_to_f32(ih));
      Wout[0 * 4096 + base] = rh;
      Wout[1 * 4096 + base] = rl;
      Wout[2 * 4096 + base] = ih;
      Wout[3 * 4096 + base] = il;
    }
  }
}

// ---------------------------------------------------------------------------
// apply (MFMA): 256 threads = 4 waves; wave handles 32 rows (2 M-tiles of
// 16x16x32), full N=64 (4 N-tiles), K=64 (2 k-steps). Block = 128 rows.
// A: lane holds x[row0+ (l&15)][8*(l>>4)+j] (k-mapping shared with B, so
// any k-permutation cancels). C/D: col = l&15, row = 4*(l>>4)+reg
// [guide, m89-verified].
// ---------------------------------------------------------------------------
__global__ __launch_bounds__(256, 2) void apply_mfma(
    const unsigned short* __restrict__ W,
    const float* __restrict__ xr,
    const float* __restrict__ xi,
    float* __restrict__ out_re,
    float* __restrict__ out_im) {  // null -> real-only
  __shared__ __align__(16) unsigned short sW[4 * PSIZE * PSIZE];  // 32 KB
  {
    const float4* src = (const float4*)W;
    float4* dst = (float4*)sW;
    for (int i = threadIdx.x; i < WSPLIT_BYTES / 16; i += 256) dst[i] = src[i];
  }
  __syncthreads();

  const int lane = threadIdx.x & 63;
  const int wave = threadIdx.x >> 6;
  const int lm = lane & 15;
  const int lg = lane >> 4;
  const long row0 = (long)blockIdx.x * 128 + (long)wave * 32;

  f32x4 accRe[2][4], accIm[2][4];
#pragma unroll
  for (int a = 0; a < 2; ++a)
#pragma unroll
    for (int b = 0; b < 4; ++b) {
      accRe[a][b] = f32x4{0.f, 0.f, 0.f, 0.f};
      accIm[a][b] = f32x4{0.f, 0.f, 0.f, 0.f};
    }

#pragma unroll
  for (int ks = 0; ks < 2; ++ks) {
    // A-fragments for both M-tiles: bf16 hi/lo of xr, xi, and -xi.
    sh8 arh[2], arl[2], aih[2], ail[2], anh[2], anl[2];
#pragma unroll
    for (int mt = 0; mt < 2; ++mt) {
      const long r = row0 + mt * 16 + lm;
      const float4* pr = (const float4*)(xr + r * PSIZE + ks * 32 + lg * 8);
      const float4* pi = (const float4*)(xi + r * PSIZE + ks * 32 + lg * 8);
      const float4 v0 = pr[0], v1 = pr[1];
      const float4 w0 = pi[0], w1 = pi[1];
      const float fr[8] = {v0.x, v0.y, v0.z, v0.w, v1.x, v1.y, v1.z, v1.w};
      const float fi[8] = {w0.x, w0.y, w0.z, w0.w, w1.x, w1.y, w1.z, w1.w};
#pragma unroll
      for (int j = 0; j < 8; ++j) {
        unsigned short h = f32_to_bf16_rn(fr[j]);
        unsigned short l = f32_to_bf16_rn(fr[j] - bf16_to_f32(h));
        arh[mt][j] = (short)h;
        arl[mt][j] = (short)l;
        h = f32_to_bf16_rn(fi[j]);
        l = f32_to_bf16_rn(fi[j] - bf16_to_f32(h));
        aih[mt][j] = (short)h;
        ail[mt][j] = (short)l;
        anh[mt][j] = (short)(h ^ 0x8000);  // exact bf16 negation
        anl[mt][j] = (short)(l ^ 0x8000);
      }
    }

#pragma unroll
    for (int nt = 0; nt < 4; ++nt) {
      const int n = nt * 16 + lm;
      const int sidx = n * 64 + (((ks * 4 + lg) ^ (n & 7)) << 3);
      const sh8 bRh = *(const sh8*)&sW[0 * 4096 + sidx];
      const sh8 bRl = *(const sh8*)&sW[1 * 4096 + sidx];
      const sh8 bIh = *(const sh8*)&sW[2 * 4096 + sidx];
      const sh8 bIl = *(const sh8*)&sW[3 * 4096 + sidx];
#pragma unroll
      for (int mt = 0; mt < 2; ++mt) {
        f32x4 cr = accRe[mt][nt];
        cr = __builtin_amdgcn_mfma_f32_16x16x32_bf16(arh[mt], bRh, cr, 0, 0, 0);
        cr = __builtin_amdgcn_mfma_f32_16x16x32_bf16(arh[mt], bRl, cr, 0, 0, 0);
        cr = __builtin_amdgcn_mfma_f32_16x16x32_bf16(arl[mt], bRh, cr, 0, 0, 0);
        cr = __builtin_amdgcn_mfma_f32_16x16x32_bf16(anh[mt], bIh, cr, 0, 0, 0);
        cr = __builtin_amdgcn_mfma_f32_16x16x32_bf16(anh[mt], bIl, cr, 0, 0, 0);
        cr = __builtin_amdgcn_mfma_f32_16x16x32_bf16(anl[mt], bIh, cr, 0, 0, 0);
        accRe[mt][nt] = cr;
        f32x4 ci = accIm[mt][nt];
        ci = __builtin_amdgcn_mfma_f32_16x16x32_bf16(arh[mt], bIh, ci, 0, 0, 0);
        ci = __builtin_amdgcn_mfma_f32_16x16x32_bf16(arh[mt], bIl, ci, 0, 0, 0);
        ci = __builtin_amdgcn_mfma_f32_16x16x32_bf16(arl[mt], bIh, ci, 0, 0, 0);
        ci = __builtin_amdgcn_mfma_f32_16x16x32_bf16(aih[mt], bRh, ci, 0, 0, 0);
        ci = __builtin_amdgcn_mfma_f32_16x16x32_bf16(aih[mt], bRl, ci, 0, 0, 0);
        ci = __builtin_amdgcn_mfma_f32_16x16x32_bf16(ail[mt], bRh, ci, 0, 0, 0);
        accIm[mt][nt] = ci;
      }
    }
  }

  // Epilogue: Kerr rotation; 16 lanes/group write 64B contiguous per store.
#pragma unroll
  for (int mt = 0; mt < 2; ++mt) {
#pragma unroll
    for (int reg = 0; reg < 4; ++reg) {
      const long row = row0 + mt * 16 + lg * 4 + reg;
#pragma unroll
      for (int nt = 0; nt < 4; ++nt) {
        const int col = nt * 16 + lm;
        const float re = accRe[mt][nt][reg];
        const float im = accIm[mt][nt][reg];
        const float p = NL_COEFF * fmaf(re, re, im * im);
        out_re[row * PSIZE + col] = fmaf(-im, p, re);
        if (out_im != nullptr) out_im[row * PSIZE + col] = fmaf(re, p, im);
      }
    }
  }
}

// ---------------------------------------------------------------------------
// tail / fallback: R9's harness-verified VALU apply, + rowStart offset.
// ---------------------------------------------------------------------------
__global__ __launch_bounds__(256, 2) void tail_kernel(
    const float* __restrict__ Usrc,   // null -> g_U_fallback
    const float* __restrict__ xr,
    const float* __restrict__ xi,
    float* __restrict__ out_re,
    float* __restrict__ out_im,
    long rowStart, long nrows) {
  __shared__ __align__(16) float sU[2 * PSIZE * PSIZE];  // 32 KB
  {
    const float4* g4 = (const float4*)((Usrc != nullptr) ? Usrc : g_U_fallback);
    float4* s4 = (float4*)sU;
    for (int i = threadIdx.x; i < (2 * PSIZE * PSIZE) / 4; i += 256)
      s4[i] = g4[i];
  }
  __syncthreads();

  const long row = rowStart + (long)blockIdx.x * 256 + threadIdx.x;
  if (row >= nrows) return;

  const float4* xr4 = (const float4*)(xr + (size_t)row * PSIZE);
  const float4* xi4 = (const float4*)(xi + (size_t)row * PSIZE);

  float aR[PSIZE], aI[PSIZE];
#pragma unroll
  for (int j = 0; j < PSIZE; ++j) { aR[j] = 0.0f; aI[j] = 0.0f; }

  const float4* su4 = (const float4*)sU;

#pragma unroll 1
  for (int kc = 0; kc < 8; ++kc) {
    const float4 a0 = xr4[2 * kc];
    const float4 a1 = xr4[2 * kc + 1];
    const float4 b0 = xi4[2 * kc];
    const float4 b1 = xi4[2 * kc + 1];
    const float4* up = su4 + kc * 4;
#pragma unroll
    for (int j = 0; j < PSIZE; ++j) {
      const float4 u0 = up[j * 32 + 0];
      const float4 u1 = up[j * 32 + 1];
      const float4 u2 = up[j * 32 + 2];
      const float4 u3 = up[j * 32 + 3];
      float r = aR[j], m = aI[j];
      r = fmaf(a0.x, u0.x, r); r = fmaf(-b0.x, u0.y, r);
      m = fmaf(a0.x, u0.y, m); m = fmaf( b0.x, u0.x, m);
      r = fmaf(a0.y, u0.z, r); r = fmaf(-b0.y, u0.w, r);
      m = fmaf(a0.y, u0.w, m); m = fmaf( b0.y, u0.z, m);
      r = fmaf(a0.z, u1.x, r); r = fmaf(-b0.z, u1.y, r);
      m = fmaf(a0.z, u1.y, m); m = fmaf( b0.z, u1.x, m);
      r = fmaf(a0.w, u1.z, r); r = fmaf(-b0.w, u1.w, r);
      m = fmaf(a0.w, u1.w, m); m = fmaf( b0.w, u1.z, m);
      r = fmaf(a1.x, u2.x, r); r = fmaf(-b1.x, u2.y, r);
      m = fmaf(a1.x, u2.y, m); m = fmaf( b1.x, u2.x, m);
      r = fmaf(a1.y, u2.z, r); r = fmaf(-b1.y, u2.w, r);
      m = fmaf(a1.y, u2.w, m); m = fmaf( b1.y, u2.z, m);
      r = fmaf(a1.z, u3.x, r); r = fmaf(-b1.z, u3.y, r);
      m = fmaf(a1.z, u3.y, m); m = fmaf( b1.z, u3.x, m);
      r = fmaf(a1.w, u3.z, r); r = fmaf(-b1.w, u3.w, r);
      m = fmaf(a1.w, u3.w, m); m = fmaf( b1.w, u3.z, m);
      aR[j] = r; aI[j] = m;
    }
  }

  float* orp = out_re + (size_t)row * PSIZE;
  float* oip = (out_im != nullptr) ? (out_im + (size_t)row * PSIZE) : nullptr;
#pragma unroll
  for (int jq = 0; jq < 16; ++jq) {
    const int j = 4 * jq;
    float4 vr, vi;
    {
      const float p = NL_COEFF * fmaf(aR[j], aR[j], aI[j] * aI[j]);
      vr.x = fmaf(-aI[j], p, aR[j]); vi.x = fmaf(aR[j], p, aI[j]);
    }
    {
      const float p = NL_COEFF * fmaf(aR[j+1], aR[j+1], aI[j+1] * aI[j+1]);
      vr.y = fmaf(-aI[j+1], p, aR[j+1]); vi.y = fmaf(aR[j+1], p, aI[j+1]);
    }
    {
      const float p = NL_COEFF * fmaf(aR[j+2], aR[j+2], aI[j+2] * aI[j+2]);
      vr.z = fmaf(-aI[j+2], p, aR[j+2]); vi.z = fmaf(aR[j+2], p, aI[j+2]);
    }
    {
      const float p = NL_COEFF * fmaf(aR[j+3], aR[j+3], aI[j+3] * aI[j+3]);
      vr.w = fmaf(-aI[j+3], p, aR[j+3]); vi.w = fmaf(aR[j+3], p, aI[j+3]);
    }
    ((float4*)orp)[jq] = vr;
    if (oip != nullptr) ((float4*)oip)[jq] = vi;
  }
}

extern "C" void kernel_launch(void* const* d_in, const int* in_sizes, int n_in,
                              void* d_out, int out_size, void* d_ws, size_t ws_size,
                              hipStream_t stream) {
  // Identify inputs by size, not position: phases has exactly 2016 elements.
  int pidx = -1;
  for (int i = 0; i < n_in; ++i) {
    if (in_sizes[i] == N_PHASES) { pidx = i; break; }
  }
  if (pidx < 0) pidx = 2;
  int xa = -1, xb = -1;
  for (int i = 0; i < n_in; ++i) {
    if (i == pidx) continue;
    if (xa < 0) xa = i;
    else if (xb < 0) xb = i;
  }
  if (xa < 0 || xb < 0) return;

  const float* phases = (const float*)d_in[pidx];
  const float* x_real = (const float*)d_in[xa];
  const float* x_imag = (const float*)d_in[xb];

  long b_in = (long)in_sizes[xa] / PSIZE;
  if ((long)in_sizes[xb] / PSIZE < b_in) b_in = (long)in_sizes[xb] / PSIZE;

  float* out = (float*)d_out;
  float* out_re = out;
  float* out_im = nullptr;
  long nrows;

  if ((long)out_size >= 2 * b_in * PSIZE) {
    const long half = (long)out_size / 2;     // planar [re | im]
    out_im = out + half;
    long cap = half / PSIZE;
    nrows = (b_in < cap) ? b_in : cap;
  } else {
    long cap = (long)out_size / PSIZE;        // real-part-only
    nrows = (b_in < cap) ? b_in : cap;
  }
  if (nrows <= 0) return;

  float* Uf32 = nullptr;
  unsigned short* Wsplit = nullptr;
  if (d_ws != nullptr && ws_size >= (size_t)WS_NEED) {
    Uf32 = (float*)d_ws;
    Wsplit = (unsigned short*)((char*)d_ws + UF32_BYTES);
  }

  build_kernel<<<1, 256, 0, stream>>>(phases, Uf32, Wsplit);

  const long ntiles = (Wsplit != nullptr) ? (nrows / 128) : 0;
  if (ntiles > 0) {
    apply_mfma<<<(int)ntiles, 256, 0, stream>>>(Wsplit, x_real, x_imag,
                                                out_re, out_im);
  }
  const long done = ntiles * 128;
  if (done < nrows) {
    const long rem = nrows - done;
    const int tblocks = (int)((rem + 255) / 256);
    tail_kernel<<<tblocks, 256, 0, stream>>>(Uf32, x_real, x_imag,
                                             out_re, out_im, done, nrows);
  }
}

// Round 4
// 269.593 us; speedup vs baseline: 13.1558x; 1.0251x over previous
//
#include <hip/hip_runtime.h>

// Photonic layer: U = product of 2016 MZI 2x2 rotations (Reck mesh), then
// out = x @ U.T (complex), then tiny first-order Kerr phase rotation.
//
// R11. R10 counters: build_kernel 104us is now the longest dispatch
// (VGPR_Count=136 < 128 state + 128 batch regs -> allocator serialized or
// spilled the batched weight loads; plus ~4000 uniform branches), apply_mfma
// <~100us (VALU-bound on scalar bf16-split emulation, ~9 ops/value).
// Changes:
//  (1) build: 64 threads / 1 wave, __launch_bounds__(64,1) -> 512-VGPR cap
//      (single block; occupancy irrelevant). Keep per-layer 32x ds_read_b128
//      batch (fits in regs now). Guards at 8-MZI-group granularity; pad
//      steps inside active groups run unconditionally (exact identity).
//  (2) apply: bf16 hi/lo split via v_cvt_pk_bf16_f32 (T12 primitive,
//      2 vals/instr), residual lo = val - hi (exact in f32), negation via
//      packed ^0x80008000. ~3.5 ops/value vs ~9.
//  (3) Everything else (MFMA tiling, swizzled W layout, launcher, tail
//      fallback) carried over from the harness-verified R10.

#define PSIZE 64
#define N_PHASES 2016
#define NLAYER 63
#define LOSS_AMP 0.99426007f
#define NL_COEFF 2.6e-17f

#define UF32_BYTES (2 * PSIZE * PSIZE * 4)    // 32 KB f32 complex U
#define WSPLIT_BYTES (4 * PSIZE * PSIZE * 2)  // 32 KB: Urh,Url,Uih,Uil bf16
#define WS_NEED (UF32_BYTES + WSPLIT_BYTES)

typedef __attribute__((ext_vector_type(8))) short sh8;    // 8 bf16 (4 VGPR)
typedef __attribute__((ext_vector_type(4))) float f32x4;  // MFMA C/D

__device__ __align__(16) float g_U_fallback[2 * PSIZE * PSIZE];

__device__ inline unsigned short f32_to_bf16_rn(float f) {
  unsigned int u = __float_as_uint(f);
  u += 0x7fffu + ((u >> 16) & 1u);   // round to nearest even
  return (unsigned short)(u >> 16);
}
__device__ inline float bf16_to_f32(unsigned short h) {
  return __uint_as_float(((unsigned int)h) << 16);
}

// v_cvt_pk_bf16_f32: dst[15:0]=bf16(a), dst[31:16]=bf16(b). No builtin on
// gfx950 (guide T12) -> inline asm. Non-volatile: pure dataflow, let the
// scheduler move it.
__device__ inline unsigned pkbf16(float a, float b) {
  unsigned r;
  asm("v_cvt_pk_bf16_f32 %0, %1, %2" : "=v"(r) : "v"(a), "v"(b));
  return r;
}
__device__ inline float lo16f(unsigned u) { return __uint_as_float(u << 16); }
__device__ inline float hi16f(unsigned u) {
  return __uint_as_float(u & 0xFFFF0000u);
}
__device__ inline sh8 mk8(unsigned a, unsigned b, unsigned c, unsigned d) {
  union { unsigned u[4]; sh8 s; } t;
  t.u[0] = a; t.u[1] = b; t.u[2] = c; t.u[3] = d;
  return t.s;
}

// ---------------------------------------------------------------------------
// build: 1 block x 64 threads (1 wave). Phase 1: weights -> LDS.
// Phase 2: thread t evolves column t of U; per-layer weights batch-loaded
// into 32 float4 regs (guarded per 8-MZI group); steps guarded per group,
// in-group pads are exact identity no-ops.
// ---------------------------------------------------------------------------
__global__ __launch_bounds__(64, 1) void build_kernel(
    const float* __restrict__ phases,
    float* __restrict__ Uf32,            // null -> g_U_fallback
    unsigned short* __restrict__ Wout) { // null -> skip split output
  __shared__ __align__(16) float2 wsm[NLAYER * 64];  // row stride 64 float2
  const int tid = threadIdx.x;

  for (int idx = tid; idx < NLAYER * 64; idx += 64) {
    const int li = idx >> 6;          // layer 0..62 (mesh layer i = li+1)
    const int m = idx & 63;           // slot 0..63 (63 = pad)
    float2 w = make_float2(1.0f, 0.0f);
    if (m <= li && m < NLAYER) {
      const int p = (li * (li + 1)) / 2 + m;
      const float th = phases[p];
      w = make_float2(LOSS_AMP * cosf(th), LOSS_AMP * sinf(th));
    }
    wsm[idx] = w;
  }
  __syncthreads();

  float ure[PSIZE], uim[PSIZE];
#pragma unroll
  for (int r = 0; r < PSIZE; ++r) {
    ure[r] = (r == tid) ? 1.0f : 0.0f;
    uim[r] = 0.0f;
  }

  for (int li = 0; li < NLAYER; ++li) {
    const float4* wrow = (const float4*)&wsm[li * 64];  // 32 quads
    float4 wb[32];
    // Batched loads, guarded per 8-MZI group (4 quads each).
#pragma unroll
    for (int g = 0; g < 8; ++g) {
      if (8 * g <= li) {
        wb[4 * g + 0] = wrow[4 * g + 0];
        wb[4 * g + 1] = wrow[4 * g + 1];
        wb[4 * g + 2] = wrow[4 * g + 2];
        wb[4 * g + 3] = wrow[4 * g + 3];
      }
    }
#pragma unroll
    for (int g = 0; g < 8; ++g) {
      if (8 * g <= li) {              // wave-uniform; ~1 branch / 8 steps
#pragma unroll
        for (int mm = 0; mm < 8; ++mm) {
          const int m = 8 * g + mm;
          if (m < NLAYER) {           // compile-time after unroll
            const float wc = (m & 1) ? wb[m >> 1].z : wb[m >> 1].x;
            const float ws = (m & 1) ? wb[m >> 1].w : wb[m >> 1].y;
            const float are = ure[m], aim = uim[m];
            const float bre = ure[m + 1], bim = uim[m + 1];
            // pads (m > li): wc=1, ws=0 -> exact no-op
            ure[m]     = fmaf(wc, are, -ws * bim);
            uim[m]     = fmaf(wc, aim,  ws * bre);
            ure[m + 1] = fmaf(wc, bre, -ws * aim);
            uim[m + 1] = fmaf(wc, bim,  ws * are);
          }
        }
      }
    }
  }

  // f32 U for tail/fallback: float2[r*64 + c] = U[r][c].
  float* Udst = (Uf32 != nullptr) ? Uf32 : g_U_fallback;
#pragma unroll
  for (int r = 0; r < PSIZE; ++r)
    ((float2*)Udst)[r * PSIZE + tid] = make_float2(ure[r], uim[r]);

  // bf16 split B-matrices: W[mat][n][k] = {Urh,Url,Uih,Uil}[n][k], k = tid.
  // 16B k-slots XOR-swizzled by (n&7) so fragment ds_read_b128 is ~2-way.
  if (Wout != nullptr) {
    const int slot = tid >> 3, kin = tid & 7;
#pragma unroll
    for (int n = 0; n < PSIZE; ++n) {
      const int base = n * 64 + ((slot ^ (n & 7)) << 3) + kin;
      const unsigned short rh = f32_to_bf16_rn(ure[n]);
      const unsigned short rl = f32_to_bf16_rn(ure[n] - bf16_to_f32(rh));
      const unsigned short ih = f32_to_bf16_rn(uim[n]);
      const unsigned short il = f32_to_bf16_rn(uim[n] - bf16_to_f32(ih));
      Wout[0 * 4096 + base] = rh;
      Wout[1 * 4096 + base] = rl;
      Wout[2 * 4096 + base] = ih;
      Wout[3 * 4096 + base] = il;
    }
  }
}

// ---------------------------------------------------------------------------
// apply (MFMA): 256 threads = 4 waves; wave handles 32 rows (2 M-tiles of
// 16x16x32), full N=64 (4 N-tiles), K=64 (2 k-steps). Block = 128 rows.
// A/B share the logical-k mapping (permutation cancels); C/D: col = l&15,
// row = 4*(l>>4)+reg [guide, m89-verified; R10 harness-verified].
// ---------------------------------------------------------------------------
__global__ __launch_bounds__(256, 2) void apply_mfma(
    const unsigned short* __restrict__ W,
    const float* __restrict__ xr,
    const float* __restrict__ xi,
    float* __restrict__ out_re,
    float* __restrict__ out_im) {  // null -> real-only
  __shared__ __align__(16) unsigned short sW[4 * PSIZE * PSIZE];  // 32 KB
  {
    const float4* src = (const float4*)W;
    float4* dst = (float4*)sW;
    for (int i = threadIdx.x; i < WSPLIT_BYTES / 16; i += 256) dst[i] = src[i];
  }
  __syncthreads();

  const int lane = threadIdx.x & 63;
  const int wave = threadIdx.x >> 6;
  const int lm = lane & 15;
  const int lg = lane >> 4;
  const long row0 = (long)blockIdx.x * 128 + (long)wave * 32;

  f32x4 accRe[2][4], accIm[2][4];
#pragma unroll
  for (int a = 0; a < 2; ++a)
#pragma unroll
    for (int b = 0; b < 4; ++b) {
      accRe[a][b] = f32x4{0.f, 0.f, 0.f, 0.f};
      accIm[a][b] = f32x4{0.f, 0.f, 0.f, 0.f};
    }

#pragma unroll
  for (int ks = 0; ks < 2; ++ks) {
    // A-fragments: bf16 hi/lo of xr, xi, -xi via v_cvt_pk_bf16_f32.
    sh8 arh[2], arl[2], aih[2], ail[2], anh[2], anl[2];
#pragma unroll
    for (int mt = 0; mt < 2; ++mt) {
      const long r = row0 + mt * 16 + lm;
      const float4* pr = (const float4*)(xr + r * PSIZE + ks * 32 + lg * 8);
      const float4* pi = (const float4*)(xi + r * PSIZE + ks * 32 + lg * 8);
      const float4 v0 = pr[0], v1 = pr[1];
      const float4 w0 = pi[0], w1 = pi[1];

      const unsigned rh0 = pkbf16(v0.x, v0.y), rh1 = pkbf16(v0.z, v0.w);
      const unsigned rh2 = pkbf16(v1.x, v1.y), rh3 = pkbf16(v1.z, v1.w);
      const unsigned rl0 = pkbf16(v0.x - lo16f(rh0), v0.y - hi16f(rh0));
      const unsigned rl1 = pkbf16(v0.z - lo16f(rh1), v0.w - hi16f(rh1));
      const unsigned rl2 = pkbf16(v1.x - lo16f(rh2), v1.y - hi16f(rh2));
      const unsigned rl3 = pkbf16(v1.z - lo16f(rh3), v1.w - hi16f(rh3));
      arh[mt] = mk8(rh0, rh1, rh2, rh3);
      arl[mt] = mk8(rl0, rl1, rl2, rl3);

      const unsigned ih0 = pkbf16(w0.x, w0.y), ih1 = pkbf16(w0.z, w0.w);
      const unsigned ih2 = pkbf16(w1.x, w1.y), ih3 = pkbf16(w1.z, w1.w);
      const unsigned il0 = pkbf16(w0.x - lo16f(ih0), w0.y - hi16f(ih0));
      const unsigned il1 = pkbf16(w0.z - lo16f(ih1), w0.w - hi16f(ih1));
      const unsigned il2 = pkbf16(w1.x - lo16f(ih2), w1.y - hi16f(ih2));
      const unsigned il3 = pkbf16(w1.z - lo16f(ih3), w1.w - hi16f(ih3));
      aih[mt] = mk8(ih0, ih1, ih2, ih3);
      ail[mt] = mk8(il0, il1, il2, il3);
      anh[mt] = mk8(ih0 ^ 0x80008000u, ih1 ^ 0x80008000u,
                    ih2 ^ 0x80008000u, ih3 ^ 0x80008000u);
      anl[mt] = mk8(il0 ^ 0x80008000u, il1 ^ 0x80008000u,
                    il2 ^ 0x80008000u, il3 ^ 0x80008000u);
    }

#pragma unroll
    for (int nt = 0; nt < 4; ++nt) {
      const int n = nt * 16 + lm;
      const int sidx = n * 64 + (((ks * 4 + lg) ^ (n & 7)) << 3);
      const sh8 bRh = *(const sh8*)&sW[0 * 4096 + sidx];
      const sh8 bRl = *(const sh8*)&sW[1 * 4096 + sidx];
      const sh8 bIh = *(const sh8*)&sW[2 * 4096 + sidx];
      const sh8 bIl = *(const sh8*)&sW[3 * 4096 + sidx];
#pragma unroll
      for (int mt = 0; mt < 2; ++mt) {
        f32x4 cr = accRe[mt][nt];
        cr = __builtin_amdgcn_mfma_f32_16x16x32_bf16(arh[mt], bRh, cr, 0, 0, 0);
        cr = __builtin_amdgcn_mfma_f32_16x16x32_bf16(arh[mt], bRl, cr, 0, 0, 0);
        cr = __builtin_amdgcn_mfma_f32_16x16x32_bf16(arl[mt], bRh, cr, 0, 0, 0);
        cr = __builtin_amdgcn_mfma_f32_16x16x32_bf16(anh[mt], bIh, cr, 0, 0, 0);
        cr = __builtin_amdgcn_mfma_f32_16x16x32_bf16(anh[mt], bIl, cr, 0, 0, 0);
        cr = __builtin_amdgcn_mfma_f32_16x16x32_bf16(anl[mt], bIh, cr, 0, 0, 0);
        accRe[mt][nt] = cr;
        f32x4 ci = accIm[mt][nt];
        ci = __builtin_amdgcn_mfma_f32_16x16x32_bf16(arh[mt], bIh, ci, 0, 0, 0);
        ci = __builtin_amdgcn_mfma_f32_16x16x32_bf16(arh[mt], bIl, ci, 0, 0, 0);
        ci = __builtin_amdgcn_mfma_f32_16x16x32_bf16(arl[mt], bIh, ci, 0, 0, 0);
        ci = __builtin_amdgcn_mfma_f32_16x16x32_bf16(aih[mt], bRh, ci, 0, 0, 0);
        ci = __builtin_amdgcn_mfma_f32_16x16x32_bf16(aih[mt], bRl, ci, 0, 0, 0);
        ci = __builtin_amdgcn_mfma_f32_16x16x32_bf16(ail[mt], bRh, ci, 0, 0, 0);
        accIm[mt][nt] = ci;
      }
    }
  }

  // Epilogue: Kerr rotation; 16-lane groups write 64B contiguous segments.
#pragma unroll
  for (int mt = 0; mt < 2; ++mt) {
#pragma unroll
    for (int reg = 0; reg < 4; ++reg) {
      const long row = row0 + mt * 16 + lg * 4 + reg;
#pragma unroll
      for (int nt = 0; nt < 4; ++nt) {
        const int col = nt * 16 + lm;
        const float re = accRe[mt][nt][reg];
        const float im = accIm[mt][nt][reg];
        const float p = NL_COEFF * fmaf(re, re, im * im);
        out_re[row * PSIZE + col] = fmaf(-im, p, re);
        if (out_im != nullptr) out_im[row * PSIZE + col] = fmaf(re, p, im);
      }
    }
  }
}

// ---------------------------------------------------------------------------
// tail / fallback: R9's harness-verified VALU apply, + rowStart offset.
// ---------------------------------------------------------------------------
__global__ __launch_bounds__(256, 2) void tail_kernel(
    const float* __restrict__ Usrc,   // null -> g_U_fallback
    const float* __restrict__ xr,
    const float* __restrict__ xi,
    float* __restrict__ out_re,
    float* __restrict__ out_im,
    long rowStart, long nrows) {
  __shared__ __align__(16) float sU[2 * PSIZE * PSIZE];  // 32 KB
  {
    const float4* g4 = (const float4*)((Usrc != nullptr) ? Usrc : g_U_fallback);
    float4* s4 = (float4*)sU;
    for (int i = threadIdx.x; i < (2 * PSIZE * PSIZE) / 4; i += 256)
      s4[i] = g4[i];
  }
  __syncthreads();

  const long row = rowStart + (long)blockIdx.x * 256 + threadIdx.x;
  if (row >= nrows) return;

  const float4* xr4 = (const float4*)(xr + (size_t)row * PSIZE);
  const float4* xi4 = (const float4*)(xi + (size_t)row * PSIZE);

  float aR[PSIZE], aI[PSIZE];
#pragma unroll
  for (int j = 0; j < PSIZE; ++j) { aR[j] = 0.0f; aI[j] = 0.0f; }

  const float4* su4 = (const float4*)sU;

#pragma unroll 1
  for (int kc = 0; kc < 8; ++kc) {
    const float4 a0 = xr4[2 * kc];
    const float4 a1 = xr4[2 * kc + 1];
    const float4 b0 = xi4[2 * kc];
    const float4 b1 = xi4[2 * kc + 1];
    const float4* up = su4 + kc * 4;
#pragma unroll
    for (int j = 0; j < PSIZE; ++j) {
      const float4 u0 = up[j * 32 + 0];
      const float4 u1 = up[j * 32 + 1];
      const float4 u2 = up[j * 32 + 2];
      const float4 u3 = up[j * 32 + 3];
      float r = aR[j], m = aI[j];
      r = fmaf(a0.x, u0.x, r); r = fmaf(-b0.x, u0.y, r);
      m = fmaf(a0.x, u0.y, m); m = fmaf( b0.x, u0.x, m);
      r = fmaf(a0.y, u0.z, r); r = fmaf(-b0.y, u0.w, r);
      m = fmaf(a0.y, u0.w, m); m = fmaf( b0.y, u0.z, m);
      r = fmaf(a0.z, u1.x, r); r = fmaf(-b0.z, u1.y, r);
      m = fmaf(a0.z, u1.y, m); m = fmaf( b0.z, u1.x, m);
      r = fmaf(a0.w, u1.z, r); r = fmaf(-b0.w, u1.w, r);
      m = fmaf(a0.w, u1.w, m); m = fmaf( b0.w, u1.z, m);
      r = fmaf(a1.x, u2.x, r); r = fmaf(-b1.x, u2.y, r);
      m = fmaf(a1.x, u2.y, m); m = fmaf( b1.x, u2.x, m);
      r = fmaf(a1.y, u2.z, r); r = fmaf(-b1.y, u2.w, r);
      m = fmaf(a1.y, u2.w, m); m = fmaf( b1.y, u2.z, m);
      r = fmaf(a1.z, u3.x, r); r = fmaf(-b1.z, u3.y, r);
      m = fmaf(a1.z, u3.y, m); m = fmaf( b1.z, u3.x, m);
      r = fmaf(a1.w, u3.z, r); r = fmaf(-b1.w, u3.w, r);
      m = fmaf(a1.w, u3.w, m); m = fmaf( b1.w, u3.z, m);
      aR[j] = r; aI[j] = m;
    }
  }

  float* orp = out_re + (size_t)row * PSIZE;
  float* oip = (out_im != nullptr) ? (out_im + (size_t)row * PSIZE) : nullptr;
#pragma unroll
  for (int jq = 0; jq < 16; ++jq) {
    const int j = 4 * jq;
    float4 vr, vi;
    {
      const float p = NL_COEFF * fmaf(aR[j], aR[j], aI[j] * aI[j]);
      vr.x = fmaf(-aI[j], p, aR[j]); vi.x = fmaf(aR[j], p, aI[j]);
    }
    {
      const float p = NL_COEFF * fmaf(aR[j+1], aR[j+1], aI[j+1] * aI[j+1]);
      vr.y = fmaf(-aI[j+1], p, aR[j+1]); vi.y = fmaf(aR[j+1], p, aI[j+1]);
    }
    {
      const float p = NL_COEFF * fmaf(aR[j+2], aR[j+2], aI[j+2] * aI[j+2]);
      vr.z = fmaf(-aI[j+2], p, aR[j+2]); vi.z = fmaf(aR[j+2], p, aI[j+2]);
    }
    {
      const float p = NL_COEFF * fmaf(aR[j+3], aR[j+3], aI[j+3] * aI[j+3]);
      vr.w = fmaf(-aI[j+3], p, aR[j+3]); vi.w = fmaf(aR[j+3], p, aI[j+3]);
    }
    ((float4*)orp)[jq] = vr;
    if (oip != nullptr) ((float4*)oip)[jq] = vi;
  }
}

extern "C" void kernel_launch(void* const* d_in, const int* in_sizes, int n_in,
                              void* d_out, int out_size, void* d_ws, size_t ws_size,
                              hipStream_t stream) {
  // Identify inputs by size, not position: phases has exactly 2016 elements.
  int pidx = -1;
  for (int i = 0; i < n_in; ++i) {
    if (in_sizes[i] == N_PHASES) { pidx = i; break; }
  }
  if (pidx < 0) pidx = 2;
  int xa = -1, xb = -1;
  for (int i = 0; i < n_in; ++i) {
    if (i == pidx) continue;
    if (xa < 0) xa = i;
    else if (xb < 0) xb = i;
  }
  if (xa < 0 || xb < 0) return;

  const float* phases = (const float*)d_in[pidx];
  const float* x_real = (const float*)d_in[xa];
  const float* x_imag = (const float*)d_in[xb];

  long b_in = (long)in_sizes[xa] / PSIZE;
  if ((long)in_sizes[xb] / PSIZE < b_in) b_in = (long)in_sizes[xb] / PSIZE;

  float* out = (float*)d_out;
  float* out_re = out;
  float* out_im = nullptr;
  long nrows;

  if ((long)out_size >= 2 * b_in * PSIZE) {
    const long half = (long)out_size / 2;     // planar [re | im]
    out_im = out + half;
    long cap = half / PSIZE;
    nrows = (b_in < cap) ? b_in : cap;
  } else {
    long cap = (long)out_size / PSIZE;        // real-part-only
    nrows = (b_in < cap) ? b_in : cap;
  }
  if (nrows <= 0) return;

  float* Uf32 = nullptr;
  unsigned short* Wsplit = nullptr;
  if (d_ws != nullptr && ws_size >= (size_t)WS_NEED) {
    Uf32 = (float*)d_ws;
    Wsplit = (unsigned short*)((char*)d_ws + UF32_BYTES);
  }

  build_kernel<<<1, 64, 0, stream>>>(phases, Uf32, Wsplit);

  const long ntiles = (Wsplit != nullptr) ? (nrows / 128) : 0;
  if (ntiles > 0) {
    apply_mfma<<<(int)ntiles, 256, 0, stream>>>(Wsplit, x_real, x_imag,
                                                out_re, out_im);
  }
  const long done = ntiles * 128;
  if (done < nrows) {
    const long rem = nrows - done;
    const int tblocks = (int)((rem + 255) / 256);
    tail_kernel<<<tblocks, 256, 0, stream>>>(Uf32, x_real, x_imag,
                                             out_re, out_im, done, nrows);
  }
}